// Round 4
// baseline (2470.915 us; speedup 1.0000x reference)
//
#include <hip/hip_runtime.h>
#include <hip/hip_bf16.h>
#include <cstdint>
#include <cstddef>

// Problem constants
#define KBLK 6
#define SL 257
#define BA 64
#define DM 1024
#define NHEAD 16
#define DRED 256
#define HDM 16
#define MR (SL * BA)     // 16448 real rows
#define MP 16512         // 129 * 128 padded rows (for out_proj staging reads only)
#define LNEPS 1e-5f

typedef __hip_bfloat16 bf16;
typedef __attribute__((ext_vector_type(8))) short short8;
typedef __attribute__((ext_vector_type(4))) short short4_t;
typedef __attribute__((ext_vector_type(4))) float f32x4;

// ---------------- async global -> LDS (16B per lane) ----------------
__device__ __forceinline__ void gld_lds16(const void* g, void* l) {
  __builtin_amdgcn_global_load_lds(
      (const __attribute__((address_space(1))) unsigned int*)g,
      (__attribute__((address_space(3))) unsigned int*)l, 16, 0, 0);
}

__device__ __forceinline__ float bf2f(short s) {
  bf16 t = *reinterpret_cast<bf16*>(&s);
  return __bfloat162float(t);
}
__device__ __forceinline__ short f2bf(float f) {
  bf16 t = __float2bfloat16(f);
  return *reinterpret_cast<short*>(&t);
}

// ---------------- weight casts ----------------
__global__ __launch_bounds__(256) void cast_bf16_kernel(const float* __restrict__ src,
                                                        bf16* __restrict__ dst, int n) {
  int i = blockIdx.x * 256 + threadIdx.x;
  int stride = gridDim.x * 256;
  for (; i < n; i += stride) dst[i] = __float2bfloat16(src[i]);
}

__global__ __launch_bounds__(256) void cast_projT_kernel(const float* __restrict__ proj,
                                                         bf16* __restrict__ dst) {
  // proj: (DM, 768) -> dst: (768, DM)
  int i = blockIdx.x * 256 + threadIdx.x;
  if (i < 768 * DM) {
    int n = i >> 10, k = i & (DM - 1);
    dst[i] = __float2bfloat16(proj[k * 768 + n]);
  }
}

// ---------------- LayerNorm ----------------
// MODE 0: x = bf16(hook); LN(hook) -> hout
// MODE 2: LN(x) -> hout
// MODE 3: LN(x) -> hout at transposed row (b*SL+s)  [ln_post]
template <int MODE>
__global__ __launch_bounds__(256) void ln_kernel(
    const float* __restrict__ hook,
    bf16* __restrict__ x, bf16* __restrict__ hout,
    const float* __restrict__ w, const float* __restrict__ bb) {
  const int row = blockIdx.x;
  const int tid = threadIdx.x;
  const size_t base = (size_t)row * DM + tid * 4;
  float vals[4];
  if (MODE == 0) {
    float4 v = *(const float4*)(hook + base);
    vals[0] = v.x; vals[1] = v.y; vals[2] = v.z; vals[3] = v.w;
    short4_t pk;
#pragma unroll
    for (int j = 0; j < 4; ++j) pk[j] = f2bf(vals[j]);
    *(short4_t*)&x[base] = pk;
  } else {
    short4_t xv = *(const short4_t*)&x[base];
#pragma unroll
    for (int j = 0; j < 4; ++j) vals[j] = bf2f(xv[j]);
  }
  float s1 = vals[0] + vals[1] + vals[2] + vals[3];
  float s2 = vals[0] * vals[0] + vals[1] * vals[1] + vals[2] * vals[2] + vals[3] * vals[3];
#pragma unroll
  for (int o = 32; o >= 1; o >>= 1) {
    s1 += __shfl_down(s1, o);
    s2 += __shfl_down(s2, o);
  }
  __shared__ float red[8];
  if ((tid & 63) == 0) {
    red[tid >> 6] = s1;
    red[4 + (tid >> 6)] = s2;
  }
  __syncthreads();
  s1 = red[0] + red[1] + red[2] + red[3];
  s2 = red[4] + red[5] + red[6] + red[7];
  const float mu = s1 * (1.f / DM);
  const float rs = rsqrtf(s2 * (1.f / DM) - mu * mu + LNEPS);
  size_t orow = row;
  if (MODE == 3) {
    int s = row >> 6, b2 = row & 63;
    orow = (size_t)b2 * SL + s;
  }
  const int c = tid * 4;
  short4_t pk;
#pragma unroll
  for (int j = 0; j < 4; ++j)
    pk[j] = f2bf((vals[j] - mu) * rs * w[c + j] + bb[c + j]);
  *(short4_t*)((char*)hout + (orow * DM + c) * 2) = pk;
}

// ---------------- MFMA attention (unchanged, validated) ----------------
__global__ __launch_bounds__(256) void attn_mfma_kernel(const bf16* __restrict__ qkv,
                                                        bf16* __restrict__ obuf) {
  __shared__ __align__(16) short ql[272][24];
  __shared__ __align__(16) short kl[272][24];
  __shared__ __align__(16) short vt[16][296];
  __shared__ __align__(16) short pl[4][16][40];
  const int bh = blockIdx.x;
  const int b = bh >> 4, h = bh & 15;
  const int tid = threadIdx.x;
  const int wave = tid >> 6, lane = tid & 63;
  const int g = lane >> 4, qi = lane & 15;

  const short8 zero8 = {0, 0, 0, 0, 0, 0, 0, 0};
  const f32x4 fzero = {0.f, 0.f, 0.f, 0.f};

  for (int task = tid; task < 1632; task += 256) {
    int a, rem;
    if (task < 544) { a = 0; rem = task; }
    else if (task < 1088) { a = 1; rem = task - 544; }
    else { a = 2; rem = task - 1088; }
    int row = rem >> 1, half = rem & 1;
    short8 v = zero8;
    if (row < SL)
      v = *(const short8*)((const short*)qkv + (size_t)(row * BA + b) * 768 + a * 256 + h * 16 + half * 8);
    if (a == 0) *(short8*)&ql[row][half * 8] = v;
    else if (a == 1) *(short8*)&kl[row][half * 8] = v;
    else {
#pragma unroll
      for (int j = 0; j < 8; ++j) vt[half * 8 + j][row] = v[j];
    }
  }
  for (int i = tid; i < 16 * 24; i += 256) vt[i / 24][272 + (i % 24)] = 0;
  __syncthreads();

  for (int t = wave; t < 17; t += 4) {
    short8 bq = zero8;
    if (g < 2) bq = *(const short8*)&ql[t * 16 + qi][g * 8];

    f32x4 st[18];
#pragma unroll
    for (int t2 = 0; t2 < 17; ++t2) {
      short8 ak = zero8;
      if (g < 2) ak = *(const short8*)&kl[t2 * 16 + qi][g * 8];
      st[t2] = __builtin_amdgcn_mfma_f32_16x16x32_bf16(ak, bq, fzero, 0, 0, 0);
    }
    float mx = -1e30f;
#pragma unroll
    for (int t2 = 0; t2 < 17; ++t2) {
#pragma unroll
      for (int r = 0; r < 4; ++r) {
        int s = t2 * 16 + g * 4 + r;
        float v = (s <= 256) ? st[t2][r] * 0.25f : -1e30f;
        st[t2][r] = v;
        mx = fmaxf(mx, v);
      }
    }
    mx = fmaxf(mx, __shfl_xor(mx, 16));
    mx = fmaxf(mx, __shfl_xor(mx, 32));
    float ls = 0.f;
#pragma unroll
    for (int t2 = 0; t2 < 17; ++t2) {
#pragma unroll
      for (int r = 0; r < 4; ++r) {
        float p = __expf(st[t2][r] - mx);
        st[t2][r] = p;
        ls += p;
      }
    }
    ls += __shfl_xor(ls, 16);
    ls += __shfl_xor(ls, 32);
    const float inv = 1.f / ls;
#pragma unroll
    for (int t2 = 0; t2 < 17; ++t2)
#pragma unroll
      for (int r = 0; r < 4; ++r) st[t2][r] *= inv;
    st[17] = fzero;

    f32x4 acc = fzero;
#pragma unroll
    for (int tt = 0; tt < 9; ++tt) {
#pragma unroll
      for (int hh = 0; hh < 2; ++hh) {
        int t2 = tt * 2 + hh;
        short4_t pk;
#pragma unroll
        for (int r = 0; r < 4; ++r) pk[r] = f2bf(st[t2][r]);
        *(short4_t*)&pl[wave][qi][hh * 16 + g * 4] = pk;
      }
      short8 pa = *(const short8*)&pl[wave][qi][g * 8];
      short8 bv = *(const short8*)&vt[qi][tt * 32 + g * 8];
      acc = __builtin_amdgcn_mfma_f32_16x16x32_bf16(pa, bv, acc, 0, 0, 0);
    }
#pragma unroll
    for (int r = 0; r < 4; ++r) {
      int qr = t * 16 + g * 4 + r;
      if (qr < SL)
        obuf[(size_t)(qr * BA + b) * DRED + h * 16 + qi] = __float2bfloat16(acc[r]);
    }
  }
}

// ---------------- 128x128 GEMM (out_proj only): x_out = x_in(RMW in-place) + A*B^T + bias
__global__ __launch_bounds__(256, 3) void gemm_op_kernel(
    const bf16* __restrict__ A, int lda,
    const bf16* __restrict__ Bw, int ldb,
    const float* __restrict__ bias,
    bf16* __restrict__ C, int ldc,
    int Kdim, int Mreal) {
  __shared__ char lds[32768];
  const int tid = threadIdx.x;
  const int wave = tid >> 6, lane = tid & 63;
  const int lrow = lane & 15, lk = lane >> 4;
  const int wr = wave >> 1, wc = wave & 1;

  const int gx = gridDim.x, gy = gridDim.y;
  const int nwg = gx * gy;
  const int orig = blockIdx.y * gx + blockIdx.x;
  const int q = nwg >> 3, r = nwg & 7;
  const int xcd = orig & 7, idx = orig >> 3;
  const int wgid = (xcd < r ? xcd * (q + 1) : r * (q + 1) + (xcd - r) * q) + idx;
  const int m0 = (wgid / gy) * 128;
  const int n0 = (wgid % gy) * 128;

  f32x4 acc[4][4];
  const f32x4 zero = {0.f, 0.f, 0.f, 0.f};
#pragma unroll
  for (int i = 0; i < 4; ++i)
#pragma unroll
    for (int j = 0; j < 4; ++j) acc[i][j] = zero;

  const int nk = Kdim >> 6;

  for (int kt = 0; kt < nk; ++kt) {
    const int k0 = kt << 6;
#pragma unroll
    for (int j = 0; j < 4; ++j) {
      int c = wave * 256 + j * 64 + lane;
      int row = c >> 3, segp = c & 7;
      int seg = segp ^ (row & 7);
      const bf16* ga = A + (size_t)(m0 + row) * lda + k0 + seg * 8;
      gld_lds16(ga, &lds[(wave * 256 + j * 64) * 16]);
      const bf16* gb = Bw + (size_t)(n0 + row) * ldb + k0 + seg * 8;
      gld_lds16(gb, &lds[16384 + (wave * 256 + j * 64) * 16]);
    }
    __syncthreads();
    const char* aL = &lds[0];
    const char* bL = aL + 16384;
#pragma unroll
    for (int kh = 0; kh < 2; ++kh) {
      short8 af[4], bfr[4];
#pragma unroll
      for (int i = 0; i < 4; ++i) {
        int rr = wr * 64 + i * 16 + lrow;
        int seg = kh * 4 + lk;
        af[i] = *(const short8*)(aL + rr * 128 + ((seg ^ (rr & 7)) << 4));
      }
#pragma unroll
      for (int j = 0; j < 4; ++j) {
        int rr = wc * 64 + j * 16 + lrow;
        int seg = kh * 4 + lk;
        bfr[j] = *(const short8*)(bL + rr * 128 + ((seg ^ (rr & 7)) << 4));
      }
#pragma unroll
      for (int i = 0; i < 4; ++i)
#pragma unroll
        for (int j = 0; j < 4; ++j)
          acc[i][j] = __builtin_amdgcn_mfma_f32_16x16x32_bf16(af[i], bfr[j], acc[i][j], 0, 0, 0);
    }
    __syncthreads();
  }

#pragma unroll
  for (int i = 0; i < 4; ++i) {
#pragma unroll
    for (int j = 0; j < 4; ++j) {
      int col = n0 + wc * 64 + j * 16 + lrow;
      float bv = bias[col];
#pragma unroll
      for (int rr = 0; rr < 4; ++rr) {
        int row = m0 + wr * 64 + i * 16 + lk * 4 + rr;
        if (row < Mreal) {
          size_t off = (size_t)row * ldc + col;
          bf16* p = C + off;
          *p = __float2bfloat16(__bfloat162float(*p) + acc[i][j][rr] + bv);
        }
      }
    }
  }
}

// ---------------- 256x256 8-wave phase-split GEMM (K=1024 shapes) ----------------
// C(M,N) = A(M,K) * Bw(N,K)^T (+ bias)
// Tiles: BM=BN=256, BK=64, 512 thr (8 waves, 2M x 4N), per-wave 128x64, acc[8][4].
// 2 LDS buffers x (A 32KB + B 32KB) = 128KB. T2 XOR-swizzle: col ^= 16 elems when row bit2.
// 4 phases per K-tile: {stage half-tiles || ds_read subtile -> raw barrier -> lgkmcnt(0)
//   -> setprio(1) 16 MFMA setprio(0) -> raw barrier}; vmcnt(0) only at tile boundary.
// Last M-tile is shifted (m0 = MR-256): epilogues must be PURE (no RMW) - overlap rows
// get identical values written twice.
// EPI 0: fp32 write (final proj)        EPI 1: bf16 Xin + acc + bias (pure, out-of-place)
// EPI 2: bf16 quickgelu(acc+bias)       EPI 3: bf16 acc+bias
// EPI 4: bf16 wm*hook + (1-wm)*(Xin + acc + bias)
template <int EPI>
__global__ __launch_bounds__(512, 2) void gemm8_kernel(
    const bf16* __restrict__ A, int lda,
    const bf16* __restrict__ Bw, int ldb,
    const float* __restrict__ bias,
    void* __restrict__ C, int ldc,
    int Kdim, int NT,
    const bf16* __restrict__ Xin,
    const float* __restrict__ hook, const float* __restrict__ alphap, int kidx) {
  __shared__ __align__(16) char lds[131072];  // [buf][A 32K | B 32K]
  const int tid = threadIdx.x;
  const int wave = tid >> 6, lane = tid & 63;
  const int lrow = lane & 15, lk = lane >> 4;
  const int wm = wave >> 2, wn = wave & 3;

  // bijective XCD swizzle (m204), n-fastest decomposition
  const int nwg = gridDim.x;
  const int orig = blockIdx.x;
  const int q = nwg >> 3, r = nwg & 7;
  const int xcd = orig & 7, idx = orig >> 3;
  const int wgid = (xcd < r ? xcd * (q + 1) : r * (q + 1) + (xcd - r) * q) + idx;
  const int mt = wgid / NT, nt = wgid % NT;
  int m0 = mt * 256;
  if (m0 > MR - 256) m0 = MR - 256;  // shifted last tile (overlap recompute, pure writes)
  const int n0 = nt * 256;

  f32x4 acc[8][4];
  const f32x4 fzero = {0.f, 0.f, 0.f, 0.f};
#pragma unroll
  for (int i = 0; i < 8; ++i)
#pragma unroll
    for (int j = 0; j < 4; ++j) acc[i][j] = fzero;

  const int nk = Kdim >> 6;

  // stage half h (0,1 = A halves; 2,3 = B halves) of K-tile kt into buffer b.
  // LDS dest linear; global source inverse-swizzled (rule #21).
  auto stageHalf = [&](int b, int kt, int h) {
    const bf16* base = (h < 2) ? A : Bw;
    const int ld = (h < 2) ? lda : ldb;
    const int row0 = (h < 2) ? m0 : n0;
    const int hh = h & 1;
    char* ldsbase = &lds[b * 65536 + (h < 2 ? 0 : 32768) + hh * 16384];
    const int k0 = kt << 6;
#pragma unroll
    for (int l = 0; l < 2; ++l) {
      int s = (wave * 2 + l) * 64 + lane;  // 16B segment index 0..1023
      int rloc = s >> 3;
      int cs = (s & 7) ^ (((rloc >> 2) & 1) << 1);
      const bf16* g = base + (size_t)(row0 + hh * 128 + rloc) * ld + k0 + cs * 8;
      gld_lds16(g, ldsbase + (wave * 2 + l) * 1024);
    }
  };
  auto readA = [&](int b, int i, int kk) -> short8 {
    int rr = wm * 128 + i * 16 + lrow;
    int cb = (kk * 64 + lk * 16) ^ (((lrow >> 2) & 1) << 5);
    return *(const short8*)&lds[b * 65536 + rr * 128 + cb];
  };
  auto readB = [&](int b, int j, int kk) -> short8 {
    int rr = wn * 64 + j * 16 + lrow;
    int cb = (kk * 64 + lk * 16) ^ (((lrow >> 2) & 1) << 5);
    return *(const short8*)&lds[b * 65536 + 32768 + rr * 128 + cb];
  };

#define PH_PRE                                          \
  __builtin_amdgcn_s_barrier();                         \
  asm volatile("s_waitcnt lgkmcnt(0)" ::: "memory");    \
  __builtin_amdgcn_sched_barrier(0);                    \
  __builtin_amdgcn_s_setprio(1);
#define PH_POST                                         \
  __builtin_amdgcn_s_setprio(0);                        \
  __builtin_amdgcn_s_barrier();

  // prologue: stage tile 0 fully, drain, barrier
#pragma unroll
  for (int h = 0; h < 4; ++h) stageHalf(0, 0, h);
  asm volatile("s_waitcnt vmcnt(0)" ::: "memory");
  __builtin_amdgcn_s_barrier();

#pragma unroll 1
  for (int kt = 0; kt < nk; ++kt) {
    const int b = kt & 1;
    const bool pf = (kt + 1 < nk);
    short8 bfr[4], af[4];
    // ---- phase 0: kk=0, ih=0; stage next A halves
    if (pf) { stageHalf(b ^ 1, kt + 1, 0); stageHalf(b ^ 1, kt + 1, 1); }
#pragma unroll
    for (int j = 0; j < 4; ++j) bfr[j] = readB(b, j, 0);
#pragma unroll
    for (int i = 0; i < 4; ++i) af[i] = readA(b, i, 0);
    PH_PRE
#pragma unroll
    for (int i = 0; i < 4; ++i)
#pragma unroll
      for (int j = 0; j < 4; ++j)
        acc[i][j] = __builtin_amdgcn_mfma_f32_16x16x32_bf16(af[i], bfr[j], acc[i][j], 0, 0, 0);
    PH_POST
    // ---- phase 1: kk=0, ih=1; stage next B halves
    if (pf) { stageHalf(b ^ 1, kt + 1, 2); stageHalf(b ^ 1, kt + 1, 3); }
#pragma unroll
    for (int i = 0; i < 4; ++i) af[i] = readA(b, i + 4, 0);
    PH_PRE
#pragma unroll
    for (int i = 0; i < 4; ++i)
#pragma unroll
      for (int j = 0; j < 4; ++j)
        acc[i + 4][j] = __builtin_amdgcn_mfma_f32_16x16x32_bf16(af[i], bfr[j], acc[i + 4][j], 0, 0, 0);
    PH_POST
    // ---- phase 2: kk=1, ih=0
#pragma unroll
    for (int j = 0; j < 4; ++j) bfr[j] = readB(b, j, 1);
#pragma unroll
    for (int i = 0; i < 4; ++i) af[i] = readA(b, i, 1);
    PH_PRE
#pragma unroll
    for (int i = 0; i < 4; ++i)
#pragma unroll
      for (int j = 0; j < 4; ++j)
        acc[i][j] = __builtin_amdgcn_mfma_f32_16x16x32_bf16(af[i], bfr[j], acc[i][j], 0, 0, 0);
    PH_POST
    // ---- phase 3: kk=1, ih=1; tile-boundary drain
#pragma unroll
    for (int i = 0; i < 4; ++i) af[i] = readA(b, i + 4, 1);
    PH_PRE
#pragma unroll
    for (int i = 0; i < 4; ++i)
#pragma unroll
      for (int j = 0; j < 4; ++j)
        acc[i + 4][j] = __builtin_amdgcn_mfma_f32_16x16x32_bf16(af[i], bfr[j], acc[i + 4][j], 0, 0, 0);
    __builtin_amdgcn_s_setprio(0);
    asm volatile("s_waitcnt vmcnt(0)" ::: "memory");
    __builtin_amdgcn_s_barrier();
  }
#undef PH_PRE
#undef PH_POST

  // ---------------- epilogue: LDS-staged, vectorized ----------------
  if (EPI == 0) {
    // fp32, two passes of 128 rows (128KB each)
#pragma unroll
    for (int half = 0; half < 2; ++half) {
      __syncthreads();
      if (wm == half) {
#pragma unroll
        for (int i = 0; i < 8; ++i)
#pragma unroll
          for (int j = 0; j < 4; ++j)
#pragma unroll
            for (int rr = 0; rr < 4; ++rr) {
              int row_l = i * 16 + lk * 4 + rr;
              int col = wn * 64 + j * 16 + lrow;
              ((float*)lds)[row_l * 256 + col] = acc[i][j][rr];
            }
      }
      __syncthreads();
      int row_l = tid >> 2, qq = tid & 3;
      size_t grow = (size_t)(m0 + half * 128 + row_l);
      const float4* src = (const float4*)&((float*)lds)[row_l * 256 + qq * 64];
      float4* dst = (float4*)&((float*)C)[grow * ldc + n0 + qq * 64];
#pragma unroll
      for (int u = 0; u < 16; ++u) dst[u] = src[u];
    }
  } else {
    float wmg = 0.f, omg = 0.f;
    if (EPI == 4) {
      wmg = 1.f / (1.f + __expf(-alphap[kidx] * 10.f));
      omg = 1.f - wmg;
    }
    __syncthreads();
#pragma unroll
    for (int i = 0; i < 8; ++i)
#pragma unroll
      for (int j = 0; j < 4; ++j)
#pragma unroll
        for (int rr = 0; rr < 4; ++rr) {
          int row = wm * 128 + i * 16 + lk * 4 + rr;
          int col = wn * 64 + j * 16 + lrow;
          float v = acc[i][j][rr] + bias[n0 + col];
          if (EPI == 2) v = v / (1.f + __expf(-1.702f * v));
          ((short*)lds)[row * 256 + col] = f2bf(v);
        }
    __syncthreads();
    int row_l = tid >> 1, hf = tid & 1;
    size_t grow = (size_t)(m0 + row_l);
    const short8* src = (const short8*)&((short*)lds)[row_l * 256 + hf * 128];
    short8* dst = (short8*)((bf16*)C + grow * ldc + n0 + hf * 128);
    if (EPI == 2 || EPI == 3) {
#pragma unroll
      for (int u = 0; u < 16; ++u) dst[u] = src[u];
    } else if (EPI == 1) {
      const short8* xin = (const short8*)(Xin + grow * ldc + n0 + hf * 128);
#pragma unroll
      for (int u = 0; u < 16; ++u) {
        short8 a = src[u], xv = xin[u], o;
#pragma unroll
        for (int e = 0; e < 8; ++e) o[e] = f2bf(bf2f(xv[e]) + bf2f(a[e]));
        dst[u] = o;
      }
    } else {  // EPI 4
      const short8* xin = (const short8*)(Xin + grow * ldc + n0 + hf * 128);
      const float* hkrow = hook + grow * ldc + n0 + hf * 128;
#pragma unroll
      for (int u = 0; u < 16; ++u) {
        short8 a = src[u], xv = xin[u], o;
        float4 h0 = *(const float4*)(hkrow + u * 8);
        float4 h1 = *(const float4*)(hkrow + u * 8 + 4);
        float hk[8] = {h0.x, h0.y, h0.z, h0.w, h1.x, h1.y, h1.z, h1.w};
#pragma unroll
        for (int e = 0; e < 8; ++e)
          o[e] = f2bf(wmg * hk[e] + omg * (bf2f(xv[e]) + bf2f(a[e])));
        dst[u] = o;
      }
    }
  }
}

// ---------------- driver ----------------
extern "C" void kernel_launch(void* const* d_in, const int* in_sizes, int n_in,
                              void* d_out, int out_size, void* d_ws, size_t ws_size,
                              hipStream_t stream) {
  const float* hook = (const float*)d_in[0];
  const float* alpha = (const float*)d_in[1];
  const float* ipw = (const float*)d_in[2];
  const float* ipb = (const float*)d_in[3];
  const float* opw = (const float*)d_in[4];
  const float* opb = (const float*)d_in[5];
  const float* l1w = (const float*)d_in[6];
  const float* l1b = (const float*)d_in[7];
  const float* l2w = (const float*)d_in[8];
  const float* l2b = (const float*)d_in[9];
  const float* fcw = (const float*)d_in[10];
  const float* fcb = (const float*)d_in[11];
  const float* cpw = (const float*)d_in[12];
  const float* cpb = (const float*)d_in[13];
  const float* lpw = (const float*)d_in[14];
  const float* lpb = (const float*)d_in[15];
  const float* proj = (const float*)d_in[16];

  char* ws = (char*)d_ws;
  size_t off = 0;
  bf16* xA = (bf16*)(ws + off); off += (size_t)MP * DM * 2;
  bf16* xB = (bf16*)(ws + off); off += (size_t)MP * DM * 2;
  bf16* hbuf = (bf16*)(ws + off); off += (size_t)MP * DM * 2;
  bf16* qkv = (bf16*)(ws + off);
  bf16* mbuf = (bf16*)qkv;  // reuse qkv region for MLP intermediate
  off += (size_t)MP * 1024 * 2;
  bf16* obuf = (bf16*)(ws + off); off += (size_t)MP * DRED * 2;
  bf16* wq = (bf16*)(ws + off); off += (size_t)KBLK * 768 * DM * 2;
  bf16* wo = (bf16*)(ws + off); off += (size_t)KBLK * DM * DRED * 2;
  bf16* wfc = (bf16*)(ws + off); off += (size_t)KBLK * DM * DM * 2;
  bf16* wcp = (bf16*)(ws + off); off += (size_t)KBLK * DM * DM * 2;
  bf16* wpj = (bf16*)(ws + off); off += (size_t)768 * DM * 2;

  // weight casts (deterministic, every call)
  cast_bf16_kernel<<<4096, 256, 0, stream>>>(ipw, wq, KBLK * 768 * DM);
  cast_bf16_kernel<<<2048, 256, 0, stream>>>(opw, wo, KBLK * DM * DRED);
  cast_bf16_kernel<<<4096, 256, 0, stream>>>(fcw, wfc, KBLK * DM * DM);
  cast_bf16_kernel<<<4096, 256, 0, stream>>>(cpw, wcp, KBLK * DM * DM);
  cast_projT_kernel<<<(768 * DM) / 256, 256, 0, stream>>>(proj, wpj);

  const dim3 gop(MP / 128, DM / 128);  // out_proj 128x128 grid
  const int MT8 = 65;                  // 256-row tiles covering 16448 (last shifted)

  bf16* xc = xA;  // current residual stream
  for (int i = 0; i < KBLK; ++i) {
    if (i == 0)
      ln_kernel<0><<<MR, 256, 0, stream>>>(hook, xc, hbuf, l1w, l1b);
    else
      ln_kernel<2><<<MR, 256, 0, stream>>>(nullptr, xc, hbuf, l1w + i * DM, l1b + i * DM);
    // qkv = LN1(x) @ ipw^T + ipb (bf16)
    gemm8_kernel<3><<<MT8 * 3, 512, 0, stream>>>(hbuf, DM, wq + (size_t)i * 768 * DM, DM,
                                                 ipb + i * 768, qkv, 768, DM, 3,
                                                 nullptr, nullptr, nullptr, 0);
    attn_mfma_kernel<<<BA * NHEAD, 256, 0, stream>>>(qkv, obuf);
    // x += attn_out @ opw^T + opb   (in-place RMW, disjoint tiles)
    gemm_op_kernel<<<gop, 256, 0, stream>>>(obuf, DRED, wo + (size_t)i * DM * DRED, DRED,
                                            opb + i * DM, xc, DM, DRED, MR);
    ln_kernel<2><<<MR, 256, 0, stream>>>(nullptr, xc, hbuf, l2w + i * DM, l2b + i * DM);
    // mbuf = quickgelu(LN2(x) @ fcw^T + fcb)
    gemm8_kernel<2><<<MT8 * 4, 512, 0, stream>>>(hbuf, DM, wfc + (size_t)i * DM * DM, DM,
                                                 fcb + i * DM, mbuf, DM, DM, 4,
                                                 nullptr, nullptr, nullptr, 0);
    // x_next = [gate with next block's hook] (x + mbuf @ cpw^T + cpb)  (pure, out-of-place)
    bf16* xn = (xc == xA) ? xB : xA;
    if (i + 1 < KBLK)
      gemm8_kernel<4><<<MT8 * 4, 512, 0, stream>>>(mbuf, DM, wcp + (size_t)i * DM * DM, DM,
                                                   cpb + i * DM, xn, DM, DM, 4,
                                                   xc, hook + (size_t)(i + 1) * MR * DM, alpha, i + 1);
    else
      gemm8_kernel<1><<<MT8 * 4, 512, 0, stream>>>(mbuf, DM, wcp + (size_t)i * DM * DM, DM,
                                                   cpb + i * DM, xn, DM, DM, 4,
                                                   xc, nullptr, nullptr, 0);
    xc = xn;
  }
  // final: LN_post (transposed to (B,S,D)) then @ proj -> d_out (fp32)
  ln_kernel<3><<<MR, 256, 0, stream>>>(nullptr, xc, hbuf, lpw, lpb);
  gemm8_kernel<0><<<MT8 * 3, 512, 0, stream>>>(hbuf, DM, wpj, DM, nullptr,
                                               (float*)d_out, 768, DM, 3,
                                               nullptr, nullptr, nullptr, 0);
}

// Round 5
// 2395.526 us; speedup vs baseline: 1.0315x; 1.0315x over previous
//
#include <hip/hip_runtime.h>
#include <hip/hip_bf16.h>
#include <cstdint>
#include <cstddef>

// Problem constants
#define KBLK 6
#define SL 257
#define BA 64
#define DM 1024
#define NHEAD 16
#define DRED 256
#define HDM 16
#define MR (SL * BA)     // 16448 real rows
#define MP 16512         // 129 * 128 padded rows (for out_proj staging reads only)
#define LNEPS 1e-5f

typedef __hip_bfloat16 bf16;
typedef __attribute__((ext_vector_type(8))) short short8;
typedef __attribute__((ext_vector_type(4))) short short4_t;
typedef __attribute__((ext_vector_type(4))) float f32x4;

// ---------------- async global -> LDS (16B per lane) ----------------
__device__ __forceinline__ void gld_lds16(const void* g, void* l) {
  __builtin_amdgcn_global_load_lds(
      (const __attribute__((address_space(1))) unsigned int*)g,
      (__attribute__((address_space(3))) unsigned int*)l, 16, 0, 0);
}

__device__ __forceinline__ float bf2f(short s) {
  bf16 t = *reinterpret_cast<bf16*>(&s);
  return __bfloat162float(t);
}
__device__ __forceinline__ short f2bf(float f) {
  bf16 t = __float2bfloat16(f);
  return *reinterpret_cast<short*>(&t);
}

// ---------------- weight casts ----------------
__global__ __launch_bounds__(256) void cast_bf16_kernel(const float* __restrict__ src,
                                                        bf16* __restrict__ dst, int n) {
  int i = blockIdx.x * 256 + threadIdx.x;
  int stride = gridDim.x * 256;
  for (; i < n; i += stride) dst[i] = __float2bfloat16(src[i]);
}

__global__ __launch_bounds__(256) void cast_projT_kernel(const float* __restrict__ proj,
                                                         bf16* __restrict__ dst) {
  // proj: (DM, 768) -> dst: (768, DM)
  int i = blockIdx.x * 256 + threadIdx.x;
  if (i < 768 * DM) {
    int n = i >> 10, k = i & (DM - 1);
    dst[i] = __float2bfloat16(proj[k * 768 + n]);
  }
}

// ---------------- LayerNorm ----------------
// MODE 0: x = bf16(hook); LN(hook) -> hout
// MODE 2: LN(x) -> hout
// MODE 3: LN(x) -> hout at transposed row (b*SL+s)  [ln_post]
template <int MODE>
__global__ __launch_bounds__(256) void ln_kernel(
    const float* __restrict__ hook,
    bf16* __restrict__ x, bf16* __restrict__ hout,
    const float* __restrict__ w, const float* __restrict__ bb) {
  const int row = blockIdx.x;
  const int tid = threadIdx.x;
  const size_t base = (size_t)row * DM + tid * 4;
  float vals[4];
  if (MODE == 0) {
    float4 v = *(const float4*)(hook + base);
    vals[0] = v.x; vals[1] = v.y; vals[2] = v.z; vals[3] = v.w;
    short4_t pk;
#pragma unroll
    for (int j = 0; j < 4; ++j) pk[j] = f2bf(vals[j]);
    *(short4_t*)&x[base] = pk;
  } else {
    short4_t xv = *(const short4_t*)&x[base];
#pragma unroll
    for (int j = 0; j < 4; ++j) vals[j] = bf2f(xv[j]);
  }
  float s1 = vals[0] + vals[1] + vals[2] + vals[3];
  float s2 = vals[0] * vals[0] + vals[1] * vals[1] + vals[2] * vals[2] + vals[3] * vals[3];
#pragma unroll
  for (int o = 32; o >= 1; o >>= 1) {
    s1 += __shfl_down(s1, o);
    s2 += __shfl_down(s2, o);
  }
  __shared__ float red[8];
  if ((tid & 63) == 0) {
    red[tid >> 6] = s1;
    red[4 + (tid >> 6)] = s2;
  }
  __syncthreads();
  s1 = red[0] + red[1] + red[2] + red[3];
  s2 = red[4] + red[5] + red[6] + red[7];
  const float mu = s1 * (1.f / DM);
  const float rs = rsqrtf(s2 * (1.f / DM) - mu * mu + LNEPS);
  size_t orow = row;
  if (MODE == 3) {
    int s = row >> 6, b2 = row & 63;
    orow = (size_t)b2 * SL + s;
  }
  const int c = tid * 4;
  short4_t pk;
#pragma unroll
  for (int j = 0; j < 4; ++j)
    pk[j] = f2bf((vals[j] - mu) * rs * w[c + j] + bb[c + j]);
  *(short4_t*)((char*)hout + (orow * DM + c) * 2) = pk;
}

// ---------------- MFMA attention (unchanged, validated) ----------------
__global__ __launch_bounds__(256) void attn_mfma_kernel(const bf16* __restrict__ qkv,
                                                        bf16* __restrict__ obuf) {
  __shared__ __align__(16) short ql[272][24];
  __shared__ __align__(16) short kl[272][24];
  __shared__ __align__(16) short vt[16][296];
  __shared__ __align__(16) short pl[4][16][40];
  const int bh = blockIdx.x;
  const int b = bh >> 4, h = bh & 15;
  const int tid = threadIdx.x;
  const int wave = tid >> 6, lane = tid & 63;
  const int g = lane >> 4, qi = lane & 15;

  const short8 zero8 = {0, 0, 0, 0, 0, 0, 0, 0};
  const f32x4 fzero = {0.f, 0.f, 0.f, 0.f};

  for (int task = tid; task < 1632; task += 256) {
    int a, rem;
    if (task < 544) { a = 0; rem = task; }
    else if (task < 1088) { a = 1; rem = task - 544; }
    else { a = 2; rem = task - 1088; }
    int row = rem >> 1, half = rem & 1;
    short8 v = zero8;
    if (row < SL)
      v = *(const short8*)((const short*)qkv + (size_t)(row * BA + b) * 768 + a * 256 + h * 16 + half * 8);
    if (a == 0) *(short8*)&ql[row][half * 8] = v;
    else if (a == 1) *(short8*)&kl[row][half * 8] = v;
    else {
#pragma unroll
      for (int j = 0; j < 8; ++j) vt[half * 8 + j][row] = v[j];
    }
  }
  for (int i = tid; i < 16 * 24; i += 256) vt[i / 24][272 + (i % 24)] = 0;
  __syncthreads();

  for (int t = wave; t < 17; t += 4) {
    short8 bq = zero8;
    if (g < 2) bq = *(const short8*)&ql[t * 16 + qi][g * 8];

    f32x4 st[18];
#pragma unroll
    for (int t2 = 0; t2 < 17; ++t2) {
      short8 ak = zero8;
      if (g < 2) ak = *(const short8*)&kl[t2 * 16 + qi][g * 8];
      st[t2] = __builtin_amdgcn_mfma_f32_16x16x32_bf16(ak, bq, fzero, 0, 0, 0);
    }
    float mx = -1e30f;
#pragma unroll
    for (int t2 = 0; t2 < 17; ++t2) {
#pragma unroll
      for (int r = 0; r < 4; ++r) {
        int s = t2 * 16 + g * 4 + r;
        float v = (s <= 256) ? st[t2][r] * 0.25f : -1e30f;
        st[t2][r] = v;
        mx = fmaxf(mx, v);
      }
    }
    mx = fmaxf(mx, __shfl_xor(mx, 16));
    mx = fmaxf(mx, __shfl_xor(mx, 32));
    float ls = 0.f;
#pragma unroll
    for (int t2 = 0; t2 < 17; ++t2) {
#pragma unroll
      for (int r = 0; r < 4; ++r) {
        float p = __expf(st[t2][r] - mx);
        st[t2][r] = p;
        ls += p;
      }
    }
    ls += __shfl_xor(ls, 16);
    ls += __shfl_xor(ls, 32);
    const float inv = 1.f / ls;
#pragma unroll
    for (int t2 = 0; t2 < 17; ++t2)
#pragma unroll
      for (int r = 0; r < 4; ++r) st[t2][r] *= inv;
    st[17] = fzero;

    f32x4 acc = fzero;
#pragma unroll
    for (int tt = 0; tt < 9; ++tt) {
#pragma unroll
      for (int hh = 0; hh < 2; ++hh) {
        int t2 = tt * 2 + hh;
        short4_t pk;
#pragma unroll
        for (int r = 0; r < 4; ++r) pk[r] = f2bf(st[t2][r]);
        *(short4_t*)&pl[wave][qi][hh * 16 + g * 4] = pk;
      }
      short8 pa = *(const short8*)&pl[wave][qi][g * 8];
      short8 bv = *(const short8*)&vt[qi][tt * 32 + g * 8];
      acc = __builtin_amdgcn_mfma_f32_16x16x32_bf16(pa, bv, acc, 0, 0, 0);
    }
#pragma unroll
    for (int r = 0; r < 4; ++r) {
      int qr = t * 16 + g * 4 + r;
      if (qr < SL)
        obuf[(size_t)(qr * BA + b) * DRED + h * 16 + qi] = __float2bfloat16(acc[r]);
    }
  }
}

// ---------------- 128x128 GEMM (out_proj only): x += A*B^T + bias (in-place RMW)
__global__ __launch_bounds__(256, 3) void gemm_op_kernel(
    const bf16* __restrict__ A, int lda,
    const bf16* __restrict__ Bw, int ldb,
    const float* __restrict__ bias,
    bf16* __restrict__ C, int ldc,
    int Kdim, int Mreal) {
  __shared__ char lds[32768];
  const int tid = threadIdx.x;
  const int wave = tid >> 6, lane = tid & 63;
  const int lrow = lane & 15, lk = lane >> 4;
  const int wr = wave >> 1, wc = wave & 1;

  const int gx = gridDim.x, gy = gridDim.y;
  const int nwg = gx * gy;
  const int orig = blockIdx.y * gx + blockIdx.x;
  const int q = nwg >> 3, r = nwg & 7;
  const int xcd = orig & 7, idx = orig >> 3;
  const int wgid = (xcd < r ? xcd * (q + 1) : r * (q + 1) + (xcd - r) * q) + idx;
  const int m0 = (wgid / gy) * 128;
  const int n0 = (wgid % gy) * 128;

  f32x4 acc[4][4];
  const f32x4 zero = {0.f, 0.f, 0.f, 0.f};
#pragma unroll
  for (int i = 0; i < 4; ++i)
#pragma unroll
    for (int j = 0; j < 4; ++j) acc[i][j] = zero;

  const int nk = Kdim >> 6;

  for (int kt = 0; kt < nk; ++kt) {
    const int k0 = kt << 6;
#pragma unroll
    for (int j = 0; j < 4; ++j) {
      int c = wave * 256 + j * 64 + lane;
      int row = c >> 3, segp = c & 7;
      int seg = segp ^ (row & 7);
      const bf16* ga = A + (size_t)(m0 + row) * lda + k0 + seg * 8;
      gld_lds16(ga, &lds[(wave * 256 + j * 64) * 16]);
      const bf16* gb = Bw + (size_t)(n0 + row) * ldb + k0 + seg * 8;
      gld_lds16(gb, &lds[16384 + (wave * 256 + j * 64) * 16]);
    }
    __syncthreads();
    const char* aL = &lds[0];
    const char* bL = aL + 16384;
#pragma unroll
    for (int kh = 0; kh < 2; ++kh) {
      short8 af[4], bfr[4];
#pragma unroll
      for (int i = 0; i < 4; ++i) {
        int rr = wr * 64 + i * 16 + lrow;
        int seg = kh * 4 + lk;
        af[i] = *(const short8*)(aL + rr * 128 + ((seg ^ (rr & 7)) << 4));
      }
#pragma unroll
      for (int j = 0; j < 4; ++j) {
        int rr = wc * 64 + j * 16 + lrow;
        int seg = kh * 4 + lk;
        bfr[j] = *(const short8*)(bL + rr * 128 + ((seg ^ (rr & 7)) << 4));
      }
#pragma unroll
      for (int i = 0; i < 4; ++i)
#pragma unroll
        for (int j = 0; j < 4; ++j)
          acc[i][j] = __builtin_amdgcn_mfma_f32_16x16x32_bf16(af[i], bfr[j], acc[i][j], 0, 0, 0);
    }
    __syncthreads();
  }

#pragma unroll
  for (int i = 0; i < 4; ++i) {
#pragma unroll
    for (int j = 0; j < 4; ++j) {
      int col = n0 + wc * 64 + j * 16 + lrow;
      float bv = bias[col];
#pragma unroll
      for (int rr = 0; rr < 4; ++rr) {
        int row = m0 + wr * 64 + i * 16 + lk * 4 + rr;
        if (row < Mreal) {
          size_t off = (size_t)row * ldc + col;
          bf16* p = C + off;
          *p = __float2bfloat16(__bfloat162float(*p) + acc[i][j][rr] + bv);
        }
      }
    }
  }
}

// ---------------- 256x256 8-wave phase-split GEMM (K=1024 shapes) ----------------
// v2: full 3-bit XOR swizzle on stage-source AND ds_read (slot ^ (row&7)) ->
// 2-way bank aliasing (free) instead of round-4's 8-way conflict.
// Everything else identical to round 4 (A halves staged ph0, B halves ph1,
// vmcnt(0)+barrier only at tile boundary; 2 raw barriers per phase; setprio).
template <int EPI>
__global__ __launch_bounds__(512, 2) void gemm8_kernel(
    const bf16* __restrict__ A, int lda,
    const bf16* __restrict__ Bw, int ldb,
    const float* __restrict__ bias,
    void* __restrict__ C, int ldc,
    int Kdim, int NT,
    const bf16* __restrict__ Xin,
    const float* __restrict__ hook, const float* __restrict__ alphap, int kidx) {
  __shared__ __align__(16) char lds[131072];  // [buf][A 32K | B 32K]
  const int tid = threadIdx.x;
  const int wave = tid >> 6, lane = tid & 63;
  const int lrow = lane & 15, lk = lane >> 4;
  const int wm = wave >> 2, wn = wave & 3;

  // bijective XCD swizzle (m204), n-fastest decomposition
  const int nwg = gridDim.x;
  const int orig = blockIdx.x;
  const int q = nwg >> 3, r = nwg & 7;
  const int xcd = orig & 7, idx = orig >> 3;
  const int wgid = (xcd < r ? xcd * (q + 1) : r * (q + 1) + (xcd - r) * q) + idx;
  const int mt = wgid / NT, nt = wgid % NT;
  int m0 = mt * 256;
  if (m0 > MR - 256) m0 = MR - 256;  // shifted last tile (overlap recompute, pure writes)
  const int n0 = nt * 256;

  f32x4 acc[8][4];
  const f32x4 fzero = {0.f, 0.f, 0.f, 0.f};
#pragma unroll
  for (int i = 0; i < 8; ++i)
#pragma unroll
    for (int j = 0; j < 4; ++j) acc[i][j] = fzero;

  const int nk = Kdim >> 6;

  // stage half h (0,1 = A halves; 2,3 = B halves) of K-tile kt into buffer b.
  // LDS dest linear (gld_lds requirement); global source inverse-swizzled with
  // the FULL 3-bit involution (s&7) ^ (row&7)  [rule #21, both-sides-or-neither].
  auto stageHalf = [&](int b, int kt, int h) {
    const bf16* base = (h < 2) ? A : Bw;
    const int ld = (h < 2) ? lda : ldb;
    const int row0 = (h < 2) ? m0 : n0;
    const int hh = h & 1;
    char* ldsbase = &lds[b * 65536 + (h < 2 ? 0 : 32768) + hh * 16384];
    const int k0 = kt << 6;
#pragma unroll
    for (int l = 0; l < 2; ++l) {
      int s = (wave * 2 + l) * 64 + lane;  // 16B segment index 0..1023 within half
      int rl = s >> 3;                     // row within half 0..127
      int cs = (s & 7) ^ (rl & 7);         // inverse-swizzled source slot
      const bf16* g = base + (size_t)(row0 + hh * 128 + rl) * ld + k0 + cs * 8;
      gld_lds16(g, ldsbase + s * 16);
    }
  };
  // reads: slot = (kk*4+lk) ^ (row&7) -> 16 rows spread across all 8 slots (2-way, free)
  auto readA = [&](int b, int i, int kk) -> short8 {
    int rr = wm * 128 + i * 16 + lrow;
    int slot = (kk * 4 + lk) ^ (rr & 7);
    return *(const short8*)&lds[b * 65536 + rr * 128 + slot * 16];
  };
  auto readB = [&](int b, int j, int kk) -> short8 {
    int rr = wn * 64 + j * 16 + lrow;
    int slot = (kk * 4 + lk) ^ (rr & 7);
    return *(const short8*)&lds[b * 65536 + 32768 + rr * 128 + slot * 16];
  };

#define PH_PRE                                          \
  __builtin_amdgcn_s_barrier();                         \
  asm volatile("s_waitcnt lgkmcnt(0)" ::: "memory");    \
  __builtin_amdgcn_sched_barrier(0);                    \
  __builtin_amdgcn_s_setprio(1);
#define PH_POST                                         \
  __builtin_amdgcn_s_setprio(0);                        \
  __builtin_amdgcn_s_barrier();

  // prologue: stage tile 0 fully, drain, barrier
#pragma unroll
  for (int h = 0; h < 4; ++h) stageHalf(0, 0, h);
  asm volatile("s_waitcnt vmcnt(0)" ::: "memory");
  __builtin_amdgcn_s_barrier();

#pragma unroll 1
  for (int kt = 0; kt < nk; ++kt) {
    const int b = kt & 1;
    const bool pf = (kt + 1 < nk);
    short8 bfr[4], af[4];
    // ---- phase 0: kk=0, ih=0; stage next A halves
    if (pf) { stageHalf(b ^ 1, kt + 1, 0); stageHalf(b ^ 1, kt + 1, 1); }
#pragma unroll
    for (int j = 0; j < 4; ++j) bfr[j] = readB(b, j, 0);
#pragma unroll
    for (int i = 0; i < 4; ++i) af[i] = readA(b, i, 0);
    PH_PRE
#pragma unroll
    for (int i = 0; i < 4; ++i)
#pragma unroll
      for (int j = 0; j < 4; ++j)
        acc[i][j] = __builtin_amdgcn_mfma_f32_16x16x32_bf16(af[i], bfr[j], acc[i][j], 0, 0, 0);
    PH_POST
    // ---- phase 1: kk=0, ih=1; stage next B halves
    if (pf) { stageHalf(b ^ 1, kt + 1, 2); stageHalf(b ^ 1, kt + 1, 3); }
#pragma unroll
    for (int i = 0; i < 4; ++i) af[i] = readA(b, i + 4, 0);
    PH_PRE
#pragma unroll
    for (int i = 0; i < 4; ++i)
#pragma unroll
      for (int j = 0; j < 4; ++j)
        acc[i + 4][j] = __builtin_amdgcn_mfma_f32_16x16x32_bf16(af[i], bfr[j], acc[i + 4][j], 0, 0, 0);
    PH_POST
    // ---- phase 2: kk=1, ih=0
#pragma unroll
    for (int j = 0; j < 4; ++j) bfr[j] = readB(b, j, 1);
#pragma unroll
    for (int i = 0; i < 4; ++i) af[i] = readA(b, i, 1);
    PH_PRE
#pragma unroll
    for (int i = 0; i < 4; ++i)
#pragma unroll
      for (int j = 0; j < 4; ++j)
        acc[i][j] = __builtin_amdgcn_mfma_f32_16x16x32_bf16(af[i], bfr[j], acc[i][j], 0, 0, 0);
    PH_POST
    // ---- phase 3: kk=1, ih=1; tile-boundary drain (cheap: loads issued >=2 phases ago)
#pragma unroll
    for (int i = 0; i < 4; ++i) af[i] = readA(b, i + 4, 1);
    PH_PRE
#pragma unroll
    for (int i = 0; i < 4; ++i)
#pragma unroll
      for (int j = 0; j < 4; ++j)
        acc[i + 4][j] = __builtin_amdgcn_mfma_f32_16x16x32_bf16(af[i], bfr[j], acc[i + 4][j], 0, 0, 0);
    __builtin_amdgcn_s_setprio(0);
    asm volatile("s_waitcnt vmcnt(0)" ::: "memory");
    __builtin_amdgcn_s_barrier();
  }
#undef PH_PRE
#undef PH_POST

  // ---------------- epilogue: LDS-staged, vectorized ----------------
  if (EPI == 0) {
    // fp32, two passes of 128 rows (128KB each)
#pragma unroll
    for (int half = 0; half < 2; ++half) {
      __syncthreads();
      if (wm == half) {
#pragma unroll
        for (int i = 0; i < 8; ++i)
#pragma unroll
          for (int j = 0; j < 4; ++j)
#pragma unroll
            for (int rr = 0; rr < 4; ++rr) {
              int row_l = i * 16 + lk * 4 + rr;
              int col = wn * 64 + j * 16 + lrow;
              ((float*)lds)[row_l * 256 + col] = acc[i][j][rr];
            }
      }
      __syncthreads();
      int row_l = tid >> 2, qq = tid & 3;
      size_t grow = (size_t)(m0 + half * 128 + row_l);
      const float4* src = (const float4*)&((float*)lds)[row_l * 256 + qq * 64];
      float4* dst = (float4*)&((float*)C)[grow * ldc + n0 + qq * 64];
#pragma unroll
      for (int u = 0; u < 16; ++u) dst[u] = src[u];
    }
  } else {
    float wmg = 0.f, omg = 0.f;
    if (EPI == 4) {
      wmg = 1.f / (1.f + __expf(-alphap[kidx] * 10.f));
      omg = 1.f - wmg;
    }
    __syncthreads();
#pragma unroll
    for (int i = 0; i < 8; ++i)
#pragma unroll
      for (int j = 0; j < 4; ++j)
#pragma unroll
        for (int rr = 0; rr < 4; ++rr) {
          int row = wm * 128 + i * 16 + lk * 4 + rr;
          int col = wn * 64 + j * 16 + lrow;
          float v = acc[i][j][rr] + bias[n0 + col];
          if (EPI == 2) v = v / (1.f + __expf(-1.702f * v));
          ((short*)lds)[row * 256 + col] = f2bf(v);
        }
    __syncthreads();
    int row_l = tid >> 1, hf = tid & 1;
    size_t grow = (size_t)(m0 + row_l);
    const short8* src = (const short8*)&((short*)lds)[row_l * 256 + hf * 128];
    short8* dst = (short8*)((bf16*)C + grow * ldc + n0 + hf * 128);
    if (EPI == 2 || EPI == 3) {
#pragma unroll
      for (int u = 0; u < 16; ++u) dst[u] = src[u];
    } else if (EPI == 1) {
      const short8* xin = (const short8*)(Xin + grow * ldc + n0 + hf * 128);
#pragma unroll
      for (int u = 0; u < 16; ++u) {
        short8 a = src[u], xv = xin[u], o;
#pragma unroll
        for (int e = 0; e < 8; ++e) o[e] = f2bf(bf2f(xv[e]) + bf2f(a[e]));
        dst[u] = o;
      }
    } else {  // EPI 4
      const short8* xin = (const short8*)(Xin + grow * ldc + n0 + hf * 128);
      const float* hkrow = hook + grow * ldc + n0 + hf * 128;
#pragma unroll
      for (int u = 0; u < 16; ++u) {
        short8 a = src[u], xv = xin[u], o;
        float4 h0 = *(const float4*)(hkrow + u * 8);
        float4 h1 = *(const float4*)(hkrow + u * 8 + 4);
        float hk[8] = {h0.x, h0.y, h0.z, h0.w, h1.x, h1.y, h1.z, h1.w};
#pragma unroll
        for (int e = 0; e < 8; ++e)
          o[e] = f2bf(wmg * hk[e] + omg * (bf2f(xv[e]) + bf2f(a[e])));
        dst[u] = o;
      }
    }
  }
}

// ---------------- driver ----------------
extern "C" void kernel_launch(void* const* d_in, const int* in_sizes, int n_in,
                              void* d_out, int out_size, void* d_ws, size_t ws_size,
                              hipStream_t stream) {
  const float* hook = (const float*)d_in[0];
  const float* alpha = (const float*)d_in[1];
  const float* ipw = (const float*)d_in[2];
  const float* ipb = (const float*)d_in[3];
  const float* opw = (const float*)d_in[4];
  const float* opb = (const float*)d_in[5];
  const float* l1w = (const float*)d_in[6];
  const float* l1b = (const float*)d_in[7];
  const float* l2w = (const float*)d_in[8];
  const float* l2b = (const float*)d_in[9];
  const float* fcw = (const float*)d_in[10];
  const float* fcb = (const float*)d_in[11];
  const float* cpw = (const float*)d_in[12];
  const float* cpb = (const float*)d_in[13];
  const float* lpw = (const float*)d_in[14];
  const float* lpb = (const float*)d_in[15];
  const float* proj = (const float*)d_in[16];

  char* ws = (char*)d_ws;
  size_t off = 0;
  bf16* xA = (bf16*)(ws + off); off += (size_t)MP * DM * 2;
  bf16* xB = (bf16*)(ws + off); off += (size_t)MP * DM * 2;
  bf16* hbuf = (bf16*)(ws + off); off += (size_t)MP * DM * 2;
  bf16* qkv = (bf16*)(ws + off);
  bf16* mbuf = (bf16*)qkv;  // reuse qkv region for MLP intermediate
  off += (size_t)MP * 1024 * 2;
  bf16* obuf = (bf16*)(ws + off); off += (size_t)MP * DRED * 2;
  bf16* wq = (bf16*)(ws + off); off += (size_t)KBLK * 768 * DM * 2;
  bf16* wo = (bf16*)(ws + off); off += (size_t)KBLK * DM * DRED * 2;
  bf16* wfc = (bf16*)(ws + off); off += (size_t)KBLK * DM * DM * 2;
  bf16* wcp = (bf16*)(ws + off); off += (size_t)KBLK * DM * DM * 2;
  bf16* wpj = (bf16*)(ws + off); off += (size_t)768 * DM * 2;

  // weight casts (deterministic, every call)
  cast_bf16_kernel<<<4096, 256, 0, stream>>>(ipw, wq, KBLK * 768 * DM);
  cast_bf16_kernel<<<2048, 256, 0, stream>>>(opw, wo, KBLK * DM * DRED);
  cast_bf16_kernel<<<4096, 256, 0, stream>>>(fcw, wfc, KBLK * DM * DM);
  cast_bf16_kernel<<<4096, 256, 0, stream>>>(cpw, wcp, KBLK * DM * DM);
  cast_projT_kernel<<<(768 * DM) / 256, 256, 0, stream>>>(proj, wpj);

  const dim3 gop(MP / 128, DM / 128);  // out_proj 128x128 grid
  const int MT8 = 65;                  // 256-row tiles covering 16448 (last shifted)

  bf16* xc = xA;  // current residual stream
  for (int i = 0; i < KBLK; ++i) {
    if (i == 0)
      ln_kernel<0><<<MR, 256, 0, stream>>>(hook, xc, hbuf, l1w, l1b);
    else
      ln_kernel<2><<<MR, 256, 0, stream>>>(nullptr, xc, hbuf, l1w + i * DM, l1b + i * DM);
    // qkv = LN1(x) @ ipw^T + ipb (bf16)
    gemm8_kernel<3><<<MT8 * 3, 512, 0, stream>>>(hbuf, DM, wq + (size_t)i * 768 * DM, DM,
                                                 ipb + i * 768, qkv, 768, DM, 3,
                                                 nullptr, nullptr, nullptr, 0);
    attn_mfma_kernel<<<BA * NHEAD, 256, 0, stream>>>(qkv, obuf);
    // x += attn_out @ opw^T + opb   (in-place RMW, disjoint tiles)
    gemm_op_kernel<<<gop, 256, 0, stream>>>(obuf, DRED, wo + (size_t)i * DM * DRED, DRED,
                                            opb + i * DM, xc, DM, DRED, MR);
    ln_kernel<2><<<MR, 256, 0, stream>>>(nullptr, xc, hbuf, l2w + i * DM, l2b + i * DM);
    // mbuf = quickgelu(LN2(x) @ fcw^T + fcb)
    gemm8_kernel<2><<<MT8 * 4, 512, 0, stream>>>(hbuf, DM, wfc + (size_t)i * DM * DM, DM,
                                                 fcb + i * DM, mbuf, DM, DM, 4,
                                                 nullptr, nullptr, nullptr, 0);
    // x_next = [gate with next block's hook] (x + mbuf @ cpw^T + cpb)  (pure, out-of-place)
    bf16* xn = (xc == xA) ? xB : xA;
    if (i + 1 < KBLK)
      gemm8_kernel<4><<<MT8 * 4, 512, 0, stream>>>(mbuf, DM, wcp + (size_t)i * DM * DM, DM,
                                                   cpb + i * DM, xn, DM, DM, 4,
                                                   xc, hook + (size_t)(i + 1) * MR * DM, alpha, i + 1);
    else
      gemm8_kernel<1><<<MT8 * 4, 512, 0, stream>>>(mbuf, DM, wcp + (size_t)i * DM * DM, DM,
                                                   cpb + i * DM, xn, DM, DM, 4,
                                                   xc, nullptr, nullptr, 0);
    xc = xn;
  }
  // final: LN_post (transposed to (B,S,D)) then @ proj -> d_out (fp32)
  ln_kernel<3><<<MR, 256, 0, stream>>>(nullptr, xc, hbuf, lpw, lpb);
  gemm8_kernel<0><<<MT8 * 3, 512, 0, stream>>>(hbuf, DM, wpj, DM, nullptr,
                                               (float*)d_out, 768, DM, 3,
                                               nullptr, nullptr, nullptr, 0);
}